// Round 12
// baseline (256.669 us; speedup 1.0000x reference)
//
#include <hip/hip_runtime.h>
#include <stdint.h>

typedef float    f32x4 __attribute__((ext_vector_type(4)));
typedef int      i32x4 __attribute__((ext_vector_type(4)));
typedef uint32_t u32;

#define NHW 401408.0   // 32*112*112

// ---- K0: per-o i8 quantization of W, in MFMA A-fragment order.
// Wq[(tap*4+of)*1024 + (kg*16 + (o&15))*16 + j] = rint(W[o][c=kg*16+j][tap]/s_o)
__global__ __launch_bounds__(64) void prep_weights(const float* __restrict__ Wg,
                                                   int8_t* __restrict__ Wq,
                                                   float* __restrict__ sc) {
  int o = blockIdx.x, c = threadIdx.x;    // 64 blocks x 64 threads
  float w[9]; float m = 0.f;
#pragma unroll
  for (int tap = 0; tap < 9; ++tap) {
    w[tap] = Wg[(o * 64 + c) * 9 + tap];
    m = fmaxf(m, fabsf(w[tap]));
  }
#pragma unroll
  for (int off = 32; off > 0; off >>= 1) m = fmaxf(m, __shfl_xor(m, off));
  float s = m / 127.f;
  float inv = (s > 0.f) ? 1.f / s : 0.f;
  if (c == 0) sc[o] = s;
  int of = o >> 4, m16 = o & 15, kg = c >> 4, j = c & 15;
#pragma unroll
  for (int tap = 0; tap < 9; ++tap) {
    int q = (int)rintf(w[tap] * inv);
    q = q > 127 ? 127 : (q < -127 ? -127 : q);
    Wq[(tap * 4 + of) * 1024 + (kg * 16 + m16) * 16 + j] = (int8_t)q;
  }
}

// ---- K1: per-channel sum / sumsq
__global__ __launch_bounds__(256) void stats_kernel(const float* __restrict__ x,
                                                    double* __restrict__ sums) {
  int blk = blockIdx.x;                       // n*64 + c
  const float4* p = (const float4*)(x + (size_t)blk * 12544);
  float s = 0.f, q = 0.f;
  for (int i = threadIdx.x; i < 3136; i += 256) {
    float4 v = p[i];
    s += (v.x + v.y) + (v.z + v.w);
    q += v.x * v.x + v.y * v.y + v.z * v.z + v.w * v.w;
  }
#pragma unroll
  for (int off = 32; off > 0; off >>= 1) {
    s += __shfl_down(s, off);
    q += __shfl_down(q, off);
  }
  __shared__ float ls[8];
  int wv = threadIdx.x >> 6;
  if ((threadIdx.x & 63) == 0) { ls[wv] = s; ls[4 + wv] = q; }
  __syncthreads();
  if (threadIdx.x == 0) {
    double S = (double)ls[0] + ls[1] + ls[2] + ls[3];
    double Q = (double)ls[4] + ls[5] + ls[6] + ls[7];
    int c = blk & 63;
    atomicAdd(&sums[c], S);
    atomicAdd(&sums[64 + c], Q);
  }
}

// ---- K2: mean/istd -> per-channel affine: xbn = fma(x, a, d)
__global__ void finalize_kernel(const double* __restrict__ sums,
                                const float* __restrict__ gamma,
                                const float* __restrict__ beta,
                                float* __restrict__ ad) {
  int c = threadIdx.x;                        // 64 threads
  double mean = sums[c] / NHW;
  double var  = sums[64 + c] / NHW - mean * mean;
  double istd = 1.0 / sqrt(var + 1e-4);
  double a = (double)gamma[c] * istd;
  double d = (double)beta[c] - mean * a;
  ad[c]      = (float)a;
  ad[64 + c] = (float)d;
}

// ---- K3: binarize + NCHW->NHWC(i8) transpose, w-padded (wp=w+1, 114 slots)
// signs[n][h][wp][c] int8; wp=0 and wp=113 zeroed.  LDS u32 transpose.
__global__ __launch_bounds__(256) void binarize_kernel(const float* __restrict__ x,
                                                       const float* __restrict__ ad,
                                                       u32* __restrict__ signs) {
  __shared__ u32 buf[64 * 29];                // [c][wu 0..27] +1 pad
  const int n = blockIdx.y, h = blockIdx.x, t = threadIdx.x;
  {
    const int c = t & 63, q = t >> 6;         // lanes span c -> coalesced loads
    const float a_c = ad[c], d_c = ad[64 + c];
    const f32x4* src = (const f32x4*)(x + (size_t)(n * 64 + c) * 12544 + h * 112 + q * 28);
#pragma unroll
    for (int i = 0; i < 7; ++i) {
      f32x4 v = src[i];
      u32 p = 0;
#pragma unroll
      for (int k = 0; k < 4; ++k) {
        float tt = fmaf(v[k], a_c, d_c);
        u32 b = (tt > 0.f) ? 0x01u : ((tt < 0.f) ? 0xFFu : 0x00u);
        p |= b << (8 * k);
      }
      buf[c * 29 + q * 7 + i] = p;            // 29 coprime 32 -> conflict-free
    }
  }
  __syncthreads();
  u32* row = signs + (size_t)(n * 112 + h) * 114 * 16;
  const int cq = t & 15, wg = t >> 4;
  if (t < 16) row[t] = 0;                     // wp=0 border
  else if (t < 32) row[113 * 16 + (t - 16)] = 0;  // wp=113 border
#pragma unroll
  for (int pass = 0; pass < 7; ++pass) {
    int w = wg + 16 * pass;                   // 0..111
    int sh = (w & 3) * 8;
    u32 o = 0;
#pragma unroll
    for (int j = 0; j < 4; ++j) {
      u32 v = buf[(cq * 4 + j) * 29 + (w >> 2)];
      o |= ((v >> sh) & 0xFFu) << (8 * j);
    }
    row[(w + 1) * 16 + cq] = o;               // 256B contiguous per pass
  }
}

// ---- K4: conv = i8 implicit GEMM, LDS-LESS: B-frags straight from L2-resident
// signs (3.3 MB working set per XCD < 4 MB L2). 512 thr = 8 waves:
// wave = (h-row r4 = wv&3, of-pair p = wv>>2), acc[2][7]. No barriers at all.
// Out-of-range halo rows (gh=-1,112) are wave-uniform SKIPS (zero contribution).
#define SROW 7296   // 114 * 64 bytes
__global__ __launch_bounds__(512, 4) void conv_kernel(
    const int8_t* __restrict__ signs, const int8_t* __restrict__ Wq,
    const float* __restrict__ sc, const float* __restrict__ bias,
    float* __restrict__ out) {
  const int tid = threadIdx.x, lane = tid & 63, wv = tid >> 6;
  const int r4 = wv & 3;                      // h-row in tile
  const int p  = wv >> 2;                     // of-pair: of in {2p, 2p+1}
  const int b = (blockIdx.x & 7) * 112 + (blockIdx.x >> 3);   // 896 = 8*112
  const int n = b / 28, th = b - n * 28;
  const int h0 = th * 4;
  const int pw = lane & 15, kg = lane >> 4;

  // per-lane column base within a signs row: wp = wf*16 + pw (+kw via imm)
  const char* sbase = (const char*)signs + (size_t)(n * 112) * SROW
                      + (size_t)pw * 64 + (size_t)kg * 16;

  i32x4 acc[2][7] = {};
#pragma unroll
  for (int tap = 0; tap < 9; ++tap) {
    const int kh = tap / 3, kw = tap - 3 * kh;
    const int gh = h0 + r4 - 1 + kh;          // wave-uniform
    if ((unsigned)gh >= 112u) continue;       // halo row: zero contribution
    i32x4 af0 = *(const i32x4*)(Wq + (tap * 4 + 2 * p) * 1024 + lane * 16);
    i32x4 af1 = *(const i32x4*)(Wq + (tap * 4 + 2 * p + 1) * 1024 + lane * 16);
    const char* row = sbase + (size_t)gh * SROW + kw * 64;
    i32x4 bf[7];
#pragma unroll
    for (int wf = 0; wf < 7; ++wf)
      bf[wf] = *(const i32x4*)(row + wf * 1024);   // 64 lanes = 1KB contiguous
#pragma unroll
    for (int wf = 0; wf < 7; ++wf) {
      acc[0][wf] = __builtin_amdgcn_mfma_i32_16x16x64_i8(af0, bf[wf], acc[0][wf], 0, 0, 0);
      acc[1][wf] = __builtin_amdgcn_mfma_i32_16x16x64_i8(af1, bf[wf], acc[1][wf], 0, 0, 0);
    }
  }

  // epilogue: direct register stores. D row = o-in-frag = kg*4+rr, col = w = pw.
  const int h = h0 + r4;
#pragma unroll
  for (int i = 0; i < 2; ++i) {
#pragma unroll
    for (int rr = 0; rr < 4; ++rr) {
      int o = (2 * p + i) * 16 + kg * 4 + rr;
      float sv = sc[o], bv = bias[o];
      float* orow = out + ((size_t)(n * 64 + o) * 112 + h) * 112;
#pragma unroll
      for (int wf = 0; wf < 7; ++wf)
        orow[wf * 16 + pw] = fmaxf(fmaf((float)acc[i][wf][rr], sv, bv), 0.f);
    }
  }
}

extern "C" void kernel_launch(void* const* d_in, const int* in_sizes, int n_in,
                              void* d_out, int out_size, void* d_ws, size_t ws_size,
                              hipStream_t stream) {
  (void)in_sizes; (void)n_in; (void)out_size; (void)ws_size;
  const float* x     = (const float*)d_in[0];
  const float* gamma = (const float*)d_in[1];
  const float* beta  = (const float*)d_in[2];
  const float* Wg    = (const float*)d_in[3];
  const float* bias  = (const float*)d_in[4];
  float* out = (float*)d_out;

  char* ws = (char*)d_ws;
  float*   ad    = (float*)ws;              // 128 f32
  double*  sums  = (double*)(ws + 512);     // 128 f64
  float*   sc    = (float*)(ws + 1536);     // 64 f32 (i8 scales)
  int8_t*  Wq    = (int8_t*)(ws + 1792);    // 36864 B fragment-ordered i8 weights
  u32*     signs = (u32*)(ws + 38656);      // 32*112*114*64 i8 = 26,148,864 B

  hipMemsetAsync(sums, 0, 128 * sizeof(double), stream);
  prep_weights<<<dim3(64), dim3(64), 0, stream>>>(Wg, Wq, sc);
  stats_kernel<<<dim3(2048), dim3(256), 0, stream>>>(x, sums);
  finalize_kernel<<<dim3(1), dim3(64), 0, stream>>>(sums, gamma, beta, ad);
  binarize_kernel<<<dim3(112, 32), dim3(256), 0, stream>>>(x, ad, signs);
  conv_kernel<<<dim3(896), dim3(512), 0, stream>>>((const int8_t*)signs, Wq, sc, bias, out);
}

// Round 13
// 235.344 us; speedup vs baseline: 1.0906x; 1.0906x over previous
//
#include <hip/hip_runtime.h>
#include <stdint.h>

typedef float    f32x4 __attribute__((ext_vector_type(4)));
typedef int      i32x4 __attribute__((ext_vector_type(4)));
typedef uint32_t u32;

#define NHW 401408.0   // 32*112*112

__device__ __forceinline__ void gload_lds16(const void* g, void* l) {
  typedef __attribute__((address_space(1))) const u32 gu32;
  typedef __attribute__((address_space(3))) u32 lu32;
  __builtin_amdgcn_global_load_lds((gu32*)g, (lu32*)l, 16, 0, 0);
}

// ---- K0: per-o i8 quantization of W, in MFMA A-fragment order.
// Wq[(tap*4+of)*1024 + (kg*16 + (o&15))*16 + j] = rint(W[o][c=kg*16+j][tap]/s_o)
// Block 0 also zero-inits the stats accumulators (replaces hipMemsetAsync).
__global__ __launch_bounds__(64) void prep_weights(const float* __restrict__ Wg,
                                                   int8_t* __restrict__ Wq,
                                                   float* __restrict__ sc,
                                                   double* __restrict__ sums) {
  int o = blockIdx.x, c = threadIdx.x;    // 64 blocks x 64 threads
  if (o == 0) { sums[c] = 0.0; sums[64 + c] = 0.0; }
  float w[9]; float m = 0.f;
#pragma unroll
  for (int tap = 0; tap < 9; ++tap) {
    w[tap] = Wg[(o * 64 + c) * 9 + tap];
    m = fmaxf(m, fabsf(w[tap]));
  }
#pragma unroll
  for (int off = 32; off > 0; off >>= 1) m = fmaxf(m, __shfl_xor(m, off));
  float s = m / 127.f;
  float inv = (s > 0.f) ? 1.f / s : 0.f;
  if (c == 0) sc[o] = s;
  int of = o >> 4, m16 = o & 15, kg = c >> 4, j = c & 15;
#pragma unroll
  for (int tap = 0; tap < 9; ++tap) {
    int q = (int)rintf(w[tap] * inv);
    q = q > 127 ? 127 : (q < -127 ? -127 : q);
    Wq[(tap * 4 + of) * 1024 + (kg * 16 + m16) * 16 + j] = (int8_t)q;
  }
}

// ---- K1: per-channel sum / sumsq
__global__ __launch_bounds__(256) void stats_kernel(const float* __restrict__ x,
                                                    double* __restrict__ sums) {
  int blk = blockIdx.x;                       // n*64 + c
  const float4* p = (const float4*)(x + (size_t)blk * 12544);
  float s = 0.f, q = 0.f;
  for (int i = threadIdx.x; i < 3136; i += 256) {
    float4 v = p[i];
    s += (v.x + v.y) + (v.z + v.w);
    q += v.x * v.x + v.y * v.y + v.z * v.z + v.w * v.w;
  }
#pragma unroll
  for (int off = 32; off > 0; off >>= 1) {
    s += __shfl_down(s, off);
    q += __shfl_down(q, off);
  }
  __shared__ float ls[8];
  int wv = threadIdx.x >> 6;
  if ((threadIdx.x & 63) == 0) { ls[wv] = s; ls[4 + wv] = q; }
  __syncthreads();
  if (threadIdx.x == 0) {
    double S = (double)ls[0] + ls[1] + ls[2] + ls[3];
    double Q = (double)ls[4] + ls[5] + ls[6] + ls[7];
    int c = blk & 63;
    atomicAdd(&sums[c], S);
    atomicAdd(&sums[64 + c], Q);
  }
}

// ---- K2: mean/istd -> per-channel affine: xbn = fma(x, a, d)
__global__ void finalize_kernel(const double* __restrict__ sums,
                                const float* __restrict__ gamma,
                                const float* __restrict__ beta,
                                float* __restrict__ ad) {
  int c = threadIdx.x;                        // 64 threads
  double mean = sums[c] / NHW;
  double var  = sums[64 + c] / NHW - mean * mean;
  double istd = 1.0 / sqrt(var + 1e-4);
  double a = (double)gamma[c] * istd;
  double d = (double)beta[c] - mean * a;
  ad[c]      = (float)a;
  ad[64 + c] = (float)d;
}

// ---- K3: binarize + NCHW->NHWC(i8) transpose, w-padded (wp=w+1, 114 slots)
// signs[n][h][wp][c] int8; wp=0 and wp=113 zeroed.  LDS u32 transpose.
__global__ __launch_bounds__(256) void binarize_kernel(const float* __restrict__ x,
                                                       const float* __restrict__ ad,
                                                       u32* __restrict__ signs) {
  __shared__ u32 buf[64 * 29];                // [c][wu 0..27] +1 pad
  const int n = blockIdx.y, h = blockIdx.x, t = threadIdx.x;
  {
    const int c = t & 63, q = t >> 6;         // lanes span c -> coalesced loads
    const float a_c = ad[c], d_c = ad[64 + c];
    const f32x4* src = (const f32x4*)(x + (size_t)(n * 64 + c) * 12544 + h * 112 + q * 28);
#pragma unroll
    for (int i = 0; i < 7; ++i) {
      f32x4 v = src[i];
      u32 p = 0;
#pragma unroll
      for (int k = 0; k < 4; ++k) {
        float tt = fmaf(v[k], a_c, d_c);
        u32 b = (tt > 0.f) ? 0x01u : ((tt < 0.f) ? 0xFFu : 0x00u);
        p |= b << (8 * k);
      }
      buf[c * 29 + q * 7 + i] = p;            // 29 coprime 32 -> conflict-free
    }
  }
  __syncthreads();
  u32* row = signs + (size_t)(n * 112 + h) * 114 * 16;
  const int cq = t & 15, wg = t >> 4;
  if (t < 16) row[t] = 0;                     // wp=0 border
  else if (t < 32) row[113 * 16 + (t - 16)] = 0;  // wp=113 border
#pragma unroll
  for (int pass = 0; pass < 7; ++pass) {
    int w = wg + 16 * pass;                   // 0..111
    int sh = (w & 3) * 8;
    u32 o = 0;
#pragma unroll
    for (int j = 0; j < 4; ++j) {
      u32 v = buf[(cq * 4 + j) * 29 + (w >> 2)];
      o |= ((v >> sh) & 0xFFu) << (8 * j);
    }
    row[(w + 1) * 16 + cq] = o;               // 256B contiguous per pass
  }
}

// ---- K4: conv = i8 implicit GEMM, full-width tile 4h x 112w x 64o (R9-proven).
// 512 thr = 8 waves: wave = (h-row r4 = wv&3, of-pair p = wv>>2), acc[2][7].
// LDS = 6 signs rows x 7296 B = 43776 -> 2 blocks/CU, 16 waves/CU.
#define SROW 7296   // 114 * 64 bytes
__global__ __launch_bounds__(512, 4) void conv_kernel(
    const int8_t* __restrict__ signs, const int8_t* __restrict__ Wq,
    const float* __restrict__ sc, const float* __restrict__ bias,
    float* __restrict__ out) {
  __shared__ __align__(16) char smem[6 * SROW];
  const int tid = threadIdx.x, lane = tid & 63, wv = tid >> 6;
  const int r4 = wv & 3;                      // h-row in tile
  const int p  = wv >> 2;                     // of-pair: of in {2p, 2p+1}
  const int b = (blockIdx.x & 7) * 112 + (blockIdx.x >> 3);   // 896 = 8*112
  const int n = b / 28, th = b - n * 28;
  const int h0 = th * 4;

  // stage 6 full-width sign rows (waves 0..5, one row each; linear gload_lds)
  if (wv < 6) {
    int gh = h0 - 1 + wv;
    char* dst = smem + wv * SROW;
    if ((unsigned)gh < 112u) {
      const char* g = (const char*)signs + (size_t)(n * 112 + gh) * SROW;
#pragma unroll
      for (int off = 0; off < 7168; off += 1024)
        gload_lds16(g + off + lane * 16, dst + off);
      if (lane < 8) gload_lds16(g + 7168 + lane * 16, dst + 7168);
    } else {
      uint4 z = {0, 0, 0, 0};
      for (int off = lane * 16; off < SROW; off += 1024) *(uint4*)(dst + off) = z;
    }
  }
  __syncthreads();

  // main loop: A = weights (M=o), B = signs (N=w). 9 tap-steps of K=64.
  i32x4 acc[2][7] = {};
  const int pw = lane & 15, kg = lane >> 4;
#pragma unroll
  for (int tap = 0; tap < 9; ++tap) {
    const int kh = tap / 3, kw = tap - 3 * kh;
    i32x4 af0 = *(const i32x4*)(Wq + (tap * 4 + 2 * p) * 1024 + lane * 16);
    i32x4 af1 = *(const i32x4*)(Wq + (tap * 4 + 2 * p + 1) * 1024 + lane * 16);
    i32x4 bf[7];
#pragma unroll
    for (int wf = 0; wf < 7; ++wf)
      bf[wf] = *(const i32x4*)(smem + ((r4 + kh) * 114 + wf * 16 + pw + kw) * 64 + kg * 16);
#pragma unroll
    for (int wf = 0; wf < 7; ++wf) {
      acc[0][wf] = __builtin_amdgcn_mfma_i32_16x16x64_i8(af0, bf[wf], acc[0][wf], 0, 0, 0);
      acc[1][wf] = __builtin_amdgcn_mfma_i32_16x16x64_i8(af1, bf[wf], acc[1][wf], 0, 0, 0);
    }
  }

  // epilogue: direct register stores. D row = o-in-frag = kg*4+rr, col = w = pw.
  const int h = h0 + r4;
#pragma unroll
  for (int i = 0; i < 2; ++i) {
#pragma unroll
    for (int rr = 0; rr < 4; ++rr) {
      int o = (2 * p + i) * 16 + kg * 4 + rr;
      float sv = sc[o], bv = bias[o];
      float* orow = out + ((size_t)(n * 64 + o) * 112 + h) * 112;
#pragma unroll
      for (int wf = 0; wf < 7; ++wf)
        orow[wf * 16 + pw] = fmaxf(fmaf((float)acc[i][wf][rr], sv, bv), 0.f);
    }
  }
}

extern "C" void kernel_launch(void* const* d_in, const int* in_sizes, int n_in,
                              void* d_out, int out_size, void* d_ws, size_t ws_size,
                              hipStream_t stream) {
  (void)in_sizes; (void)n_in; (void)out_size; (void)ws_size;
  const float* x     = (const float*)d_in[0];
  const float* gamma = (const float*)d_in[1];
  const float* beta  = (const float*)d_in[2];
  const float* Wg    = (const float*)d_in[3];
  const float* bias  = (const float*)d_in[4];
  float* out = (float*)d_out;

  char* ws = (char*)d_ws;
  float*   ad    = (float*)ws;              // 128 f32
  double*  sums  = (double*)(ws + 512);     // 128 f64
  float*   sc    = (float*)(ws + 1536);     // 64 f32 (i8 scales)
  int8_t*  Wq    = (int8_t*)(ws + 1792);    // 36864 B fragment-ordered i8 weights
  u32*     signs = (u32*)(ws + 38656);      // 32*112*114*64 i8 = 26,148,864 B

  prep_weights<<<dim3(64), dim3(64), 0, stream>>>(Wg, Wq, sc, sums);
  stats_kernel<<<dim3(2048), dim3(256), 0, stream>>>(x, sums);
  finalize_kernel<<<dim3(1), dim3(64), 0, stream>>>(sums, gamma, beta, ad);
  binarize_kernel<<<dim3(112, 32), dim3(256), 0, stream>>>(x, ad, signs);
  conv_kernel<<<dim3(896), dim3(512), 0, stream>>>((const int8_t*)signs, Wq, sc, bias, out);
}